// Round 5
// baseline (228.468 us; speedup 1.0000x reference)
//
#include <hip/hip_runtime.h>

// CIN cross-network, fused MFMA implementation (f16 inputs, fp32 accum).
// Round 8: RESUBMIT of round 7 (bench infra failed twice; no counters, no
// correctness signal -> no theory update).
// Round 7: round-6 32x32x16 structure + K-SPLIT ACCUMULATORS (8 chains).
//  - Round-6 regression diagnosis: only 4 acc chains -> same-chain reissue
//    interval ~52 cyc < 32x32 MFMA dep latency -> MFMA pipe idled ~25%
//    (MfmaUtil 48 vs 57 predicted). Split acc by mh-parity -> 8 chains,
//    interval ~100 cyc. Halves summed before epilogue.
//  - launch_bounds(256,2): acc needs 128 VGPR; the old (256,3) budget
//    (~170 unified regs) was too tight. 8 waves/CU is enough at 96% issue.
// Carried over verified pieces: 32x32 fragment mappings (round-6 passed),
// m-major x0, d-major xk, 256-thr blocks, 4 waves x 4 batches, no barriers.
//
// Fragment layouts (32x32x16 f16), correctness-verified in round 6:
//   A[row][k]: row = lane&31, k = (lane>>5)*8 + j      (j = half index 0..7)
//   B[k][col]: col = lane&31, k = (lane>>5)*8 + j
//   C/D:       col = lane&31, row = (reg&3) + 8*(reg>>2) + 4*(lane>>5)

typedef _Float16 half8 __attribute__((ext_vector_type(8)));
typedef _Float16 half4 __attribute__((ext_vector_type(4)));
typedef _Float16 half2v __attribute__((ext_vector_type(2)));
typedef float f32x16 __attribute__((ext_vector_type(16)));

#define OUT_STRIDE 192
#define X0B 512   // x0 batch stride (m-major: m*16 + d, 32x16 halfs)
#define XKR 72    // xk row stride: 64 + 8 pad (16B-aligned)
#define XKB 1152  // xk batch stride

// ---------------------------------------------------------------------------
// Fused weight repack for 32x32x16 B-fragments (round-6 verified):
// dst[((t*NKB + kb)*64 + lane)*8 + j] = (f16) W[k -> (m,h)][n],
//   k = kb*16 + (lane>>5)*8 + j,  n = t*32 + (lane&31),  t in {0,1}.
__global__ void prep_w_all(const float* __restrict__ W0,
                           const float* __restrict__ W1,
                           const float* __restrict__ W2,
                           _Float16* __restrict__ dst) {
  int e = blockIdx.x * 256 + threadIdx.x;   // e < 327680
  const float* W;
  int logH, nkbLog, le;
  if (e < 65536)       { W = W0; logH = 5; nkbLog = 6; le = e; }
  else if (e < 196608) { W = W1; logH = 6; nkbLog = 7; le = e - 65536; }
  else                 { W = W2; logH = 6; nkbLog = 7; le = e - 196608; }
  int j    = le & 7;
  int lane = (le >> 3) & 63;
  int rest = le >> 9;
  int kb   = rest & ((1 << nkbLog) - 1);
  int t    = rest >> nkbLog;
  int k    = kb * 16 + ((lane >> 5) << 3) + j;
  int H    = 1 << logH;
  int m    = k >> logH, h = k & (H - 1);
  int n    = t * 32 + (lane & 31);
  dst[e] = (_Float16)W[(m * H + h) * 64 + n];
}

// ---------------------------------------------------------------------------
// One layer for one wave's 4 private batches (2 pairs of 2).
// NHB: 16-wide h-blocks per m (2 for H=32, 1st layer; 4 for H=64).
// NKB = 32*NHB K-blocks of 16.
// av[p][mh] = xk 8-vector at h = mh*16 + (lane>>5)*8 + j, d = lane&15,
//             batch = p*2 + ((lane>>4)&1), held in registers.
// x0s is M-MAJOR: x0s[b*X0B + m*16 + d].
template<int NHB, bool LAST>
__device__ __forceinline__ void run_layer32(
    const _Float16* __restrict__ Wp, const half8 (&av)[2][NHB],
    const _Float16* x0s, _Float16* xkw, float* __restrict__ out,
    long gb0, int loff, int lane, int dl, int pb, int kg)
{
  const int NKB = 32 * NHB;
  // 8 independent accumulator chains: [pair][t][mh-parity].
  f32x16 acc[2][2][2];
#pragma unroll
  for (int p = 0; p < 2; ++p)
#pragma unroll
    for (int t = 0; t < 2; ++t)
#pragma unroll
      for (int ks = 0; ks < 2; ++ks)
#pragma unroll
        for (int rr = 0; rr < 16; ++rr) acc[p][t][ks][rr] = 0.f;

  const _Float16* Wl = Wp + lane * 8;
  const _Float16* x0l = x0s + pb * X0B + dl;   // this lane's batch within pair

#pragma unroll 2
  for (int m = 0; m < 32; ++m) {
    // x0 scalar per pair for this m (m-major: 2-way conflict max -> free).
    half2v xs2[2];
#pragma unroll
    for (int p = 0; p < 2; ++p) {
      _Float16 x = x0l[p * 2 * X0B + m * 16];
      xs2[p] = (half2v){x, x};
    }
#pragma unroll
    for (int mh = 0; mh < NHB; ++mh) {
      const int kb = m * NHB + mh;
      const int ks = mh & 1;   // static (mh unrolled) -> stays in registers
      half8 Bf0 = *(const half8*)(Wl + (size_t)(0 * NKB + kb) * 512);
      half8 Bf1 = *(const half8*)(Wl + (size_t)(1 * NKB + kb) * 512);
#pragma unroll
      for (int p = 0; p < 2; ++p) {
        half8 af;
        half2v* ap = (half2v*)&af;
        const half2v* vp = (const half2v*)&av[p][mh];
#pragma unroll
        for (int j2 = 0; j2 < 4; ++j2) ap[j2] = vp[j2] * xs2[p];
        acc[p][0][ks] = __builtin_amdgcn_mfma_f32_32x32x16_f16(af, Bf0, acc[p][0][ks], 0, 0, 0);
        acc[p][1][ks] = __builtin_amdgcn_mfma_f32_32x32x16_f16(af, Bf1, acc[p][1][ks], 0, 0, 0);
      }
    }
  }

  // Epilogue (round-6 verified mapping). Sum the K-split halves first.
  // C/D: col n = lane&31, row = (reg&3)+8*(reg>>2)+4*kg;
  // row>>4 = reg>>3 selects batch within pair, d = row&15.
#pragma unroll
  for (int p = 0; p < 2; ++p) {
#pragma unroll
    for (int t = 0; t < 2; ++t) {
      f32x16 a = acc[p][t][0] + acc[p][t][1];
      float s0 = 0.f, s1 = 0.f;
#pragma unroll
      for (int reg = 0; reg < 16; ++reg) {
        float v = a[reg];
        v = v > 0.f ? v : 0.f;
        const int pbq = reg >> 3;
        const int d = (reg & 3) + 8 * ((reg >> 2) & 1) + 4 * kg;
        if (!LAST)
          xkw[(p * 2 + pbq) * XKB + d * XKR + t * 32 + (lane & 31)] = (_Float16)v;
        if (pbq == 0) s0 += v; else s1 += v;
      }
      s0 += __shfl_xor(s0, 32);
      s1 += __shfl_xor(s1, 32);
      if (kg == 0) {   // lanes 0..31, n = lane
        out[(gb0 + p * 2 + 0) * OUT_STRIDE + loff + t * 32 + lane] = s0;
        out[(gb0 + p * 2 + 1) * OUT_STRIDE + loff + t * 32 + lane] = s1;
      }
    }
  }
}

__global__ __launch_bounds__(256, 2) void cin_main(
    const float* __restrict__ emb, const _Float16* __restrict__ Wall,
    float* __restrict__ out)
{
  // x0: 16 batches * 512 f16 (m-major) = 16384 B
  // xk: 16 batches * 1152 f16 (16 d rows of stride 72) = 36864 B
  // total 53248 B. VGPR ~160-200 -> 2 waves/SIMD (8 waves/CU).
  __shared__ __align__(16) _Float16 lds[16 * X0B + 16 * XKB];
  const int lane = threadIdx.x & 63;
  const int wv = threadIdx.x >> 6;
  const int dl = lane & 15;            // d for A/av reads
  const int pb = (lane >> 4) & 1;      // batch-within-pair for A rows
  const int kg = lane >> 5;            // K-group
  const long gb0 = (long)blockIdx.x * 16 + wv * 4;

  _Float16* x0w = &lds[wv * 4 * X0B];
  _Float16* xkw = &lds[16 * X0B + wv * 4 * XKB];

  // Stage this wave's 4 batches: emb is (m,d) row-major = the LDS layout.
#pragma unroll
  for (int bb = 0; bb < 4; ++bb) {
    const float* src = emb + (gb0 + bb) * 512;
    _Float16* dstb = x0w + bb * X0B;
#pragma unroll
    for (int i = 0; i < 2; ++i) {
      int f = i * 256 + lane * 4;
      float4 v = *(const float4*)(src + f);
      half4 h = {(_Float16)v.x, (_Float16)v.y, (_Float16)v.z, (_Float16)v.w};
      *(half4*)(dstb + f) = h;
    }
  }
  // All LDS regions are wave-private: program order + waitcnt suffice.

  // Layer 1: av from x0 (xk==x0; h indexes the m-major m axis).
  // One-time strided u16 gathers.
  half8 av1[2][2];
#pragma unroll
  for (int p = 0; p < 2; ++p)
#pragma unroll
    for (int mh = 0; mh < 2; ++mh)
#pragma unroll
      for (int j = 0; j < 8; ++j)
        av1[p][mh][j] =
            x0w[(p * 2 + pb) * X0B + (mh * 16 + kg * 8 + j) * 16 + dl];
  run_layer32<2, false>(Wall, av1, x0w, xkw, out, gb0, 0, lane, dl, pb, kg);

  // Layer 2: av from xk (d-major [d][h]); aligned half8 reads.
  half8 av2[2][4];
#pragma unroll
  for (int p = 0; p < 2; ++p)
#pragma unroll
    for (int mh = 0; mh < 4; ++mh)
      av2[p][mh] = *(const half8*)(xkw + (p * 2 + pb) * XKB + dl * XKR +
                                   mh * 16 + kg * 8);
  run_layer32<4, false>(Wall + 65536, av2, x0w, xkw, out, gb0, 64, lane, dl, pb, kg);

  // Layer 3: reload av (layer 2 rewrote xk).
#pragma unroll
  for (int p = 0; p < 2; ++p)
#pragma unroll
    for (int mh = 0; mh < 4; ++mh)
      av2[p][mh] = *(const half8*)(xkw + (p * 2 + pb) * XKB + dl * XKR +
                                   mh * 16 + kg * 8);
  run_layer32<4, true>(Wall + 196608, av2, x0w, xkw, out, gb0, 128, lane, dl, pb, kg);
}

extern "C" void kernel_launch(void* const* d_in, const int* in_sizes, int n_in,
                              void* d_out, int out_size, void* d_ws, size_t ws_size,
                              hipStream_t stream) {
  const float* emb = (const float*)d_in[0];
  const float* W0  = (const float*)d_in[1];
  const float* W1  = (const float*)d_in[2];
  const float* W2  = (const float*)d_in[3];
  float* out = (float*)d_out;
  _Float16* ws = (_Float16*)d_ws;   // needs 327680 f16 = 640 KB

  // Single fused weight repack (327680 elements).
  prep_w_all<<<1280, 256, 0, stream>>>(W0, W1, W2, ws);

  // 16384 batches / 16 per block = 1024 blocks of 256 threads (4 waves x 4 b).
  cin_main<<<1024, 256, 0, stream>>>(emb, ws, out);
}

// Round 6
// 212.252 us; speedup vs baseline: 1.0764x; 1.0764x over previous
//
#include <hip/hip_runtime.h>

// CIN cross-network, fused MFMA implementation (f16 inputs, fp32 accum).
// Round 9: REVERT to round-5 16x16x32 structure (best verified, 138.4 us;
// 32x32 path falsified twice) + EXPLICIT B-PREFETCH software pipeline.
//  - Diagnosis: round-5 time ~= MFMA(82.9us) + VALU(52.7us) serial => near
//    zero overlap; B-fragment L2 loads (~200cy) are issued in the same
//    (m,hi) group that consumes them -> exposed latency every group.
//  - Fix: double-buffered Bf[2][4] in registers; group kb issues loads for
//    kb+1 into the other slot BEFORE kb's MFMAs. Issue-to-use distance
//    becomes one compute group (~120+ cyc). Slot parity is a template
//    constant (static indexing, no scratch).
// Carried over verified pieces: 16x16x32 fragment mappings, m-major x0
// (round-5 conflict fix), d-major xk, 256-thr blocks, 4 waves x 4 private
// batches, no barriers.

typedef _Float16 half8 __attribute__((ext_vector_type(8)));
typedef _Float16 half4 __attribute__((ext_vector_type(4)));
typedef _Float16 half2v __attribute__((ext_vector_type(2)));
typedef float f32x4 __attribute__((ext_vector_type(4)));

#define OUT_STRIDE 192
#define X0B 512   // x0 batch stride (m-major: m*16 + d, 32x16 halfs)
#define XKR 72    // xk row stride: 64 + 8 pad (16B-aligned)
#define XKB 1152  // xk batch stride

// ---------------------------------------------------------------------------
// Fused weight repack (verified 16x16 mapping, all 3 layers):
// dst[base + ((t*NKB + kb)*64 + lane)*8 + j] =
//     (f16) W[k -> (m,h)][n = t*16 + (lane&15)],  k = kb*32 + (lane>>4)*8 + j
__global__ void prep_w_all(const float* __restrict__ W0,
                           const float* __restrict__ W1,
                           const float* __restrict__ W2,
                           _Float16* __restrict__ dst) {
  int e = blockIdx.x * 256 + threadIdx.x;   // e < 327680
  const float* W;
  int logH, nkbLog, le;
  if (e < 65536)       { W = W0; logH = 5; nkbLog = 5; le = e; }
  else if (e < 196608) { W = W1; logH = 6; nkbLog = 6; le = e - 65536; }
  else                 { W = W2; logH = 6; nkbLog = 6; le = e - 196608; }
  int j    = le & 7;
  int lane = (le >> 3) & 63;
  int rr   = lane & 15, qq = lane >> 4;
  int rest = le >> 9;
  int kb   = rest & ((1 << nkbLog) - 1);
  int t    = rest >> nkbLog;
  int k    = kb * 32 + qq * 8 + j;
  int H    = 1 << logH;
  int m    = k >> logH, h = k & (H - 1);
  int n    = t * 16 + rr;
  dst[e] = (_Float16)W[(m * H + h) * 64 + n];
}

// ---------------------------------------------------------------------------
// One pipelined (m,*) step: prefetch B group kb+1 into slot cur^1, then
// compute group(s) kb from slot cur. P0 = parity of m*NHI (template const,
// so all Bf indices are compile-time after hi-unroll).
template<int NHI, int P0>
__device__ __forceinline__ void cin_step(
    const _Float16* __restrict__ Wl, const half8 (&av)[4][NHI],
    const _Float16* __restrict__ x0s, f32x4 (&acc)[4][4],
    half8 (&Bf)[2][4], int m, int r)
{
  const int NKB = 32 * NHI;
  // x0 scalar per batch for this m (m-major: conflict-free, round-5 verified).
  half2v xs2[4];
#pragma unroll
  for (int b = 0; b < 4; ++b) {
    _Float16 x = x0s[b * X0B + m * 16 + r];
    xs2[b] = (half2v){x, x};
  }
#pragma unroll
  for (int hi = 0; hi < NHI; ++hi) {
    const int kb  = m * NHI + hi;
    const int cur = (P0 + hi) & 1;                 // compile-time
    const int kbn = (kb + 1 < NKB) ? kb + 1 : kb;  // clamp at layer end
    // Prefetch next group's B-fragments (L2) into the other slot; in flight
    // across this group's MFMAs.
#pragma unroll
    for (int t = 0; t < 4; ++t)
      Bf[cur ^ 1][t] = *(const half8*)(Wl + (size_t)(t * NKB + kbn) * 512);
#pragma unroll
    for (int b = 0; b < 4; ++b) {
      half8 af;
      half2v* ap = (half2v*)&af;
      const half2v* vp = (const half2v*)&av[b][hi];
#pragma unroll
      for (int j2 = 0; j2 < 4; ++j2) ap[j2] = vp[j2] * xs2[b];
#pragma unroll
      for (int t = 0; t < 4; ++t)
        acc[b][t] = __builtin_amdgcn_mfma_f32_16x16x32_f16(
            af, Bf[cur][t], acc[b][t], 0, 0, 0);
    }
  }
}

// ---------------------------------------------------------------------------
// One layer for one wave's 4 private batches.
// NHI: number of 32-wide h-blocks (1 for H=32, 2 for H=64). K-blocks: NKB=32*NHI.
// av[b][hi] = xk-vector (8 f16 at h = hi*32 + q*8 + j) held in registers.
// x0s is M-MAJOR: x0s[b*X0B + m*16 + d].
template<int NHI, bool LAST>
__device__ __forceinline__ void run_layer(
    const _Float16* __restrict__ Wp, const half8 (&av)[4][NHI],
    const _Float16* x0s, _Float16* xkw, float* __restrict__ out,
    long gb0, int loff, int lane, int r, int q)
{
  const int NKB = 32 * NHI;
  f32x4 acc[4][4];
#pragma unroll
  for (int b = 0; b < 4; ++b)
#pragma unroll
    for (int t = 0; t < 4; ++t) acc[b][t] = (f32x4){0.f, 0.f, 0.f, 0.f};

  const _Float16* Wl = Wp + lane * 8;

  // Pipeline prologue: load group kb=0 into slot 0.
  half8 Bf[2][4];
#pragma unroll
  for (int t = 0; t < 4; ++t)
    Bf[0][t] = *(const half8*)(Wl + (size_t)(t * NKB) * 512);

  // m-pair loop (same 2-m body granularity as the verified round-5 kernel).
  // Parity of kb at m: (m*NHI)&1 -> 0 for even m; NHI&1 for odd m.
  for (int mp = 0; mp < 16; ++mp) {
    cin_step<NHI, 0>(Wl, av, x0s, acc, Bf, 2 * mp, r);
    cin_step<NHI, (NHI & 1)>(Wl, av, x0s, acc, Bf, 2 * mp + 1, r);
  }

  // Epilogue (round-5 verified). C/D layout: col n = r, row d = q*4 + reg.
#pragma unroll
  for (int b = 0; b < 4; ++b) {
#pragma unroll
    for (int t = 0; t < 4; ++t) {
      float s = 0.f;
#pragma unroll
      for (int rr = 0; rr < 4; ++rr) {
        float v = acc[b][t][rr];
        v = v > 0.f ? v : 0.f;
        s += v;
        if (!LAST)
          xkw[b * XKB + (q * 4 + rr) * XKR + t * 16 + r] = (_Float16)v;
      }
      s += __shfl_xor(s, 16);
      s += __shfl_xor(s, 32);
      if (q == 0)
        out[(gb0 + b) * OUT_STRIDE + loff + t * 16 + r] = s;
    }
  }
}

__global__ __launch_bounds__(256, 3) void cin_main(
    const float* __restrict__ emb, const _Float16* __restrict__ Wall,
    float* __restrict__ out)
{
  // x0: 16 batches * 512 f16 (m-major) = 16384 B
  // xk: 16 batches * 1152 f16 (16 d rows of stride 72) = 36864 B
  // total 53248 B -> 3 blocks/CU.
  __shared__ __align__(16) _Float16 lds[16 * X0B + 16 * XKB];
  const int lane = threadIdx.x & 63;
  const int wv = threadIdx.x >> 6;
  const int r = lane & 15, q = lane >> 4;
  const long gb0 = (long)blockIdx.x * 16 + wv * 4;

  _Float16* x0w = &lds[wv * 4 * X0B];
  _Float16* xkw = &lds[16 * X0B + wv * 4 * XKB];

  // Stage this wave's 4 batches: emb is (m,d) row-major = the LDS layout.
#pragma unroll
  for (int bb = 0; bb < 4; ++bb) {
    const float* src = emb + (gb0 + bb) * 512;
    _Float16* dstb = x0w + bb * X0B;
#pragma unroll
    for (int i = 0; i < 2; ++i) {
      int f = i * 256 + lane * 4;
      float4 v = *(const float4*)(src + f);
      half4 h = {(_Float16)v.x, (_Float16)v.y, (_Float16)v.z, (_Float16)v.w};
      *(half4*)(dstb + f) = h;
    }
  }
  // All LDS regions are wave-private: program order + waitcnt suffice.

  // Layer 1: A-vectors from x0 (xk==x0, indexed by h along the m axis).
  // m-major layout -> 8 strided u16 reads per batch (one-time, outside loop).
  half8 av1[4][1];
#pragma unroll
  for (int b = 0; b < 4; ++b) {
#pragma unroll
    for (int j = 0; j < 8; ++j)
      av1[b][0][j] = x0w[b * X0B + (q * 8 + j) * 16 + r];
  }
  run_layer<1, false>(Wall, av1, x0w, xkw, out, gb0, 0, lane, r, q);

  // Layer 2: A-vectors from xk (h = hi*32 + q*8 + j), d-major xk layout.
  half8 av2[4][2];
#pragma unroll
  for (int b = 0; b < 4; ++b)
#pragma unroll
    for (int hi = 0; hi < 2; ++hi)
      av2[b][hi] = *(const half8*)(xkw + b * XKB + r * XKR + hi * 32 + q * 8);
  run_layer<2, false>(Wall + 65536, av2, x0w, xkw, out, gb0, 64, lane, r, q);

  // Layer 3: reload A-vectors (layer 2 rewrote xk).
#pragma unroll
  for (int b = 0; b < 4; ++b)
#pragma unroll
    for (int hi = 0; hi < 2; ++hi)
      av2[b][hi] = *(const half8*)(xkw + b * XKB + r * XKR + hi * 32 + q * 8);
  run_layer<2, true>(Wall + 196608, av2, x0w, xkw, out, gb0, 128, lane, r, q);
}

extern "C" void kernel_launch(void* const* d_in, const int* in_sizes, int n_in,
                              void* d_out, int out_size, void* d_ws, size_t ws_size,
                              hipStream_t stream) {
  const float* emb = (const float*)d_in[0];
  const float* W0  = (const float*)d_in[1];
  const float* W1  = (const float*)d_in[2];
  const float* W2  = (const float*)d_in[3];
  float* out = (float*)d_out;
  _Float16* ws = (_Float16*)d_ws;   // needs 327680 f16 = 640 KB

  // Single fused weight repack (327680 elements).
  prep_w_all<<<1280, 256, 0, stream>>>(W0, W1, W2, ws);

  // 16384 batches / 16 per block = 1024 blocks of 256 threads (4 waves x 4 b).
  cin_main<<<1024, 256, 0, stream>>>(emb, ws, out);
}

// Round 7
// 211.994 us; speedup vs baseline: 1.0777x; 1.0012x over previous
//
#include <hip/hip_runtime.h>

// CIN cross-network, fused MFMA implementation (f16 inputs, fp32 accum).
// Round 10: round-5 kernel (best verified, 138.4us) + KB-MAJOR W LAYOUT.
//  - Round-9 lesson: source-level prefetch is rescheduled away by the
//    compiler (MfmaUtil fell, spill traffic appeared). Don't fight the
//    scheduler; delete work instead.
//  - The 4 B-loads per (m,hi) group were 64-128KB apart (t-major layout):
//    each load needs its own 64-bit address chain (~10-14 VALU/group).
//    Repack W kb-major: ((kb*4 + t)*64 + lane)*8 + j -> one 4KB block per
//    group; loads are base + {0,1024,2048,3072} immediates, one running
//    offset add per group. Also makes W a single sequential L2 stream.
//  - Inner (lane,j) fragment mapping is UNTOUCHED (verified in round 5);
//    only the outer block index is permuted, in both repack and consumer.
// Carried over verified pieces: 16x16x32 fragments, m-major x0, d-major xk,
// 256-thr blocks, 4 waves x 4 private batches, no barriers, unroll-2 m-loop.

typedef _Float16 half8 __attribute__((ext_vector_type(8)));
typedef _Float16 half4 __attribute__((ext_vector_type(4)));
typedef _Float16 half2v __attribute__((ext_vector_type(2)));
typedef float f32x4 __attribute__((ext_vector_type(4)));

#define OUT_STRIDE 192
#define X0B 512   // x0 batch stride (m-major: m*16 + d, 32x16 halfs)
#define XKR 72    // xk row stride: 64 + 8 pad (16B-aligned)
#define XKB 1152  // xk batch stride

// ---------------------------------------------------------------------------
// Fused weight repack, kb-major blocks:
// dst[((kb*4 + t)*64 + lane)*8 + j] = (f16) W[k -> (m,h)][n],
//   k = kb*32 + (lane>>4)*8 + j,  n = t*16 + (lane&15).
// (Same per-element mapping as the round-5-verified layout; only the outer
//  block order changed from (t*NKB + kb) to (kb*4 + t).)
__global__ void prep_w_all(const float* __restrict__ W0,
                           const float* __restrict__ W1,
                           const float* __restrict__ W2,
                           _Float16* __restrict__ dst) {
  int e = blockIdx.x * 256 + threadIdx.x;   // e < 327680
  const float* W;
  int logH, le;
  if (e < 65536)       { W = W0; logH = 5; le = e; }
  else if (e < 196608) { W = W1; logH = 6; le = e - 65536; }
  else                 { W = W2; logH = 6; le = e - 196608; }
  int j    = le & 7;
  int lane = (le >> 3) & 63;
  int rest = le >> 9;
  int t    = rest & 3;          // kb-major: t is now the low field
  int kb   = rest >> 2;
  int k    = kb * 32 + ((lane >> 4) << 3) + j;
  int H    = 1 << logH;
  int m    = k >> logH, h = k & (H - 1);
  int n    = t * 16 + (lane & 15);
  dst[e] = (_Float16)W[(m * H + h) * 64 + n];
}

// ---------------------------------------------------------------------------
// One layer for one wave's 4 private batches.
// NHI: number of 32-wide h-blocks (1 for H=32, 2 for H=64). K-blocks: NKB=32*NHI.
// av[b][hi] = xk-vector (8 f16 at h = hi*32 + q*8 + j) held in registers.
// x0s is M-MAJOR: x0s[b*X0B + m*16 + d].
template<int NHI, bool LAST>
__device__ __forceinline__ void run_layer(
    const _Float16* __restrict__ Wp, const half8 (&av)[4][NHI],
    const _Float16* x0s, _Float16* xkw, float* __restrict__ out,
    long gb0, int loff, int lane, int r, int q)
{
  f32x4 acc[4][4];
#pragma unroll
  for (int b = 0; b < 4; ++b)
#pragma unroll
    for (int t = 0; t < 4; ++t) acc[b][t] = (f32x4){0.f, 0.f, 0.f, 0.f};

  const _Float16* Wlane = Wp + lane * 8;
  int woff = 0;   // running offset in halfs: group kb lives at kb*2048

#pragma unroll 2
  for (int m = 0; m < 32; ++m) {
    // x0 scalar per batch for this m (m-major: conflict-free, round-5
    // verified). b*X0B folds into the 16-bit ds imm offset.
    half2v xs2[4];
#pragma unroll
    for (int b = 0; b < 4; ++b) {
      _Float16 x = x0s[b * X0B + m * 16 + r];
      xs2[b] = (half2v){x, x};
    }
#pragma unroll
    for (int hi = 0; hi < NHI; ++hi) {
      // 4 contiguous fragments: byte offsets 0/1024/2048/3072 from the
      // group base -> immediate-offset loads off one running address.
      half8 Bf[4];
#pragma unroll
      for (int t = 0; t < 4; ++t)
        Bf[t] = *(const half8*)(Wlane + woff + hi * 2048 + t * 512);
#pragma unroll
      for (int b = 0; b < 4; ++b) {
        half8 af;
        half2v* ap = (half2v*)&af;
        const half2v* vp = (const half2v*)&av[b][hi];
#pragma unroll
        for (int j2 = 0; j2 < 4; ++j2) ap[j2] = vp[j2] * xs2[b];
#pragma unroll
        for (int t = 0; t < 4; ++t)
          acc[b][t] = __builtin_amdgcn_mfma_f32_16x16x32_f16(
              af, Bf[t], acc[b][t], 0, 0, 0);
      }
    }
    woff += NHI * 2048;
  }

  // Epilogue (round-5 verified). C/D layout: col n = r, row d = q*4 + reg.
#pragma unroll
  for (int b = 0; b < 4; ++b) {
#pragma unroll
    for (int t = 0; t < 4; ++t) {
      float s = 0.f;
#pragma unroll
      for (int rr = 0; rr < 4; ++rr) {
        float v = acc[b][t][rr];
        v = v > 0.f ? v : 0.f;
        s += v;
        if (!LAST)
          xkw[b * XKB + (q * 4 + rr) * XKR + t * 16 + r] = (_Float16)v;
      }
      s += __shfl_xor(s, 16);
      s += __shfl_xor(s, 32);
      if (q == 0)
        out[(gb0 + b) * OUT_STRIDE + loff + t * 16 + r] = s;
    }
  }
}

__global__ __launch_bounds__(256, 3) void cin_main(
    const float* __restrict__ emb, const _Float16* __restrict__ Wall,
    float* __restrict__ out)
{
  // x0: 16 batches * 512 f16 (m-major) = 16384 B
  // xk: 16 batches * 1152 f16 (16 d rows of stride 72) = 36864 B
  // total 53248 B -> 3 blocks/CU.
  __shared__ __align__(16) _Float16 lds[16 * X0B + 16 * XKB];
  const int lane = threadIdx.x & 63;
  const int wv = threadIdx.x >> 6;
  const int r = lane & 15, q = lane >> 4;
  const long gb0 = (long)blockIdx.x * 16 + wv * 4;

  _Float16* x0w = &lds[wv * 4 * X0B];
  _Float16* xkw = &lds[16 * X0B + wv * 4 * XKB];

  // Stage this wave's 4 batches: emb is (m,d) row-major = the LDS layout.
#pragma unroll
  for (int bb = 0; bb < 4; ++bb) {
    const float* src = emb + (gb0 + bb) * 512;
    _Float16* dstb = x0w + bb * X0B;
#pragma unroll
    for (int i = 0; i < 2; ++i) {
      int f = i * 256 + lane * 4;
      float4 v = *(const float4*)(src + f);
      half4 h = {(_Float16)v.x, (_Float16)v.y, (_Float16)v.z, (_Float16)v.w};
      *(half4*)(dstb + f) = h;
    }
  }
  // All LDS regions are wave-private: program order + waitcnt suffice.

  // Layer 1: A-vectors from x0 (xk==x0, indexed by h along the m axis).
  // m-major layout -> 8 strided u16 reads per batch (one-time, outside loop).
  half8 av1[4][1];
#pragma unroll
  for (int b = 0; b < 4; ++b) {
#pragma unroll
    for (int j = 0; j < 8; ++j)
      av1[b][0][j] = x0w[b * X0B + (q * 8 + j) * 16 + r];
  }
  run_layer<1, false>(Wall, av1, x0w, xkw, out, gb0, 0, lane, r, q);

  // Layer 2: A-vectors from xk (h = hi*32 + q*8 + j), d-major xk layout.
  half8 av2[4][2];
#pragma unroll
  for (int b = 0; b < 4; ++b)
#pragma unroll
    for (int hi = 0; hi < 2; ++hi)
      av2[b][hi] = *(const half8*)(xkw + b * XKB + r * XKR + hi * 32 + q * 8);
  run_layer<2, false>(Wall + 65536, av2, x0w, xkw, out, gb0, 64, lane, r, q);

  // Layer 3: reload A-vectors (layer 2 rewrote xk).
#pragma unroll
  for (int b = 0; b < 4; ++b)
#pragma unroll
    for (int hi = 0; hi < 2; ++hi)
      av2[b][hi] = *(const half8*)(xkw + b * XKB + r * XKR + hi * 32 + q * 8);
  run_layer<2, true>(Wall + 196608, av2, x0w, xkw, out, gb0, 128, lane, r, q);
}

extern "C" void kernel_launch(void* const* d_in, const int* in_sizes, int n_in,
                              void* d_out, int out_size, void* d_ws, size_t ws_size,
                              hipStream_t stream) {
  const float* emb = (const float*)d_in[0];
  const float* W0  = (const float*)d_in[1];
  const float* W1  = (const float*)d_in[2];
  const float* W2  = (const float*)d_in[3];
  float* out = (float*)d_out;
  _Float16* ws = (_Float16*)d_ws;   // needs 327680 f16 = 640 KB

  // Single fused weight repack (327680 elements).
  prep_w_all<<<1280, 256, 0, stream>>>(W0, W1, W2, ws);

  // 16384 batches / 16 per block = 1024 blocks of 256 threads (4 waves x 4 b).
  cin_main<<<1024, 256, 0, stream>>>(emb, ws, out);
}